// Round 15
// baseline (192.162 us; speedup 1.0000x reference)
//
#include <hip/hip_runtime.h>

#define N_ATOMS 8192
#define DIM 64
#define N_MOL 256
#define KS 16
#define KCH (N_ATOMS / KS)   // 512 k per split
#define BM 64
#define BN 64
#define BK 64
#define NSTEP (KCH / BK)     // 8
#define TILE_ELEMS (BM * BK) // 4096 ushorts = 8 KB per k-step image

typedef __attribute__((ext_vector_type(8))) short short8v;
typedef __attribute__((ext_vector_type(4))) float f32x4;
typedef unsigned short ushort_t;

// f32 -> bf16 RTNE (inputs finite)
__device__ __forceinline__ ushort_t f2bf(float x) {
    unsigned u = __float_as_uint(x);
    u += 0x7fffu + ((u >> 16) & 1u);
    return (ushort_t)(u >> 16);
}
__device__ __forceinline__ float bf2f(ushort_t u) {
    return __uint_as_float(((unsigned)u) << 16);
}

// async global->LDS, 16B per lane, LDS dest = wave-uniform base + lane*16
__device__ __forceinline__ void gload16(const void* gsrc, void* ldst) {
    __builtin_amdgcn_global_load_lds(
        (const __attribute__((address_space(1))) void*)gsrc,
        (__attribute__((address_space(3))) void*)ldst, 16, 0, 0);
}

// ---- pack SAf32 -> SAbf (bf16, dense 256 x 8192, row stride N_ATOMS) ----
__global__ __launch_bounds__(256) void packsa_kernel(
        const float* __restrict__ SAf32, ushort_t* __restrict__ SAbf) {
    const size_t i = ((size_t)blockIdx.x * 256 + threadIdx.x) * 8;
    float4 x0 = *(const float4*)(SAf32 + i);
    float4 x1 = *(const float4*)(SAf32 + i + 4);
    short8v v;
    v[0] = (short)f2bf(x0.x); v[1] = (short)f2bf(x0.y);
    v[2] = (short)f2bf(x0.z); v[3] = (short)f2bf(x0.w);
    v[4] = (short)f2bf(x1.x); v[5] = (short)f2bf(x1.y);
    v[6] = (short)f2bf(x1.z); v[7] = (short)f2bf(x1.w);
    *(short8v*)(SAbf + i) = v;
}

// ---- fused linear: v = (FIRST ? embed : vprev); h = relu(W v + b)
// writes hT (bf16 [DIM][N_ATOMS]); if !LAST writes vnext = h (f32);
// if LAST instead accumulates segsum(h) into out via scan+atomicAdd.
template <int FIRST, int LAST>
__global__ __launch_bounds__(256) void fused_linear_kernel(
        const int* __restrict__ fp, const float* __restrict__ table,
        const float* __restrict__ vprev, const int* __restrict__ seg,
        const float* __restrict__ W, const float* __restrict__ b,
        float* __restrict__ vnext, ushort_t* __restrict__ hT,
        float* __restrict__ out) {
    __shared__ float Ws[DIM][DIM + 1];
    __shared__ float vsT[DIM][36];
    __shared__ int segs[32];

    const int t = threadIdx.x;
    const int n0 = blockIdx.x * 32;
    if (LAST && t < 32) segs[t] = seg[n0 + t];
    for (int i = t; i < DIM * DIM; i += 256) Ws[i >> 6][i & 63] = W[i];
    for (int i = t; i < 32 * DIM; i += 256) {
        const int nl = i >> 6, d = i & 63;
        const size_t n = n0 + nl;
        float val;
        if (FIRST) val = table[(size_t)fp[n] * DIM + d];
        else       val = vprev[n * DIM + d];
        vsT[d][nl] = val;
    }
    __syncthreads();

    const int e = t & 63;
    const int g = t >> 6;
    float acc[8];
    const float be = b[e];
#pragma unroll
    for (int i = 0; i < 8; ++i) acc[i] = be;

    for (int d = 0; d < DIM; ++d) {
        const float w = Ws[e][d];
        const float4* vp = (const float4*)&vsT[d][g * 8];
        float4 x0 = vp[0], x1 = vp[1];
        acc[0] += w * x0.x; acc[1] += w * x0.y; acc[2] += w * x0.z; acc[3] += w * x0.w;
        acc[4] += w * x1.x; acc[5] += w * x1.y; acc[6] += w * x1.z; acc[7] += w * x1.w;
    }

    ushort_t hb[8];
    float seg_acc = 0.f;
    int prev = LAST ? segs[g * 8] : 0;
#pragma unroll
    for (int i = 0; i < 8; ++i) {
        float hv = acc[i] > 0.f ? acc[i] : 0.f;
        if (LAST) {
            const int m = segs[g * 8 + i];
            if (m != prev) {
                atomicAdd(&out[(size_t)prev * DIM + e], seg_acc);
                seg_acc = 0.f; prev = m;
            }
            seg_acc += hv;
        } else {
            vnext[(size_t)(n0 + g * 8 + i) * DIM + e] = hv;
        }
        hb[i] = f2bf(hv);
    }
    if (LAST) atomicAdd(&out[(size_t)prev * DIM + e], seg_acc);
    *(short8v*)(hT + (size_t)e * N_ATOMS + n0 + g * 8) = *(short8v*)&hb[0];
}

// ---- layer-0 mega kernel: one pass over f32 A per (row,k) chunk:
//   vnext += A@h0 (MFMA), AbfT = tiled bf16(A), SAf32 += segment col-sums.
// AbfT layout: tile (bx,by) at (bx*KS+by)*BM*KCH; within: ks*TILE_ELEMS + LDS image
// (r*BK + ((s^(r&7))<<3)) — i.e. the exact staged/swizzled order, so consumers
// load it linearly (16B/lane, contiguous 64 KB/block stream).
__global__ __launch_bounds__(256) void matmul_cvtsa_kernel(
        const float* __restrict__ A, const int* __restrict__ seg,
        ushort_t* __restrict__ AbfT, float* __restrict__ SAf32,
        const ushort_t* __restrict__ hT, float* __restrict__ vnext) {
    __shared__ ushort_t Asw[2][BM * BK];   // 2 x 8 KB
    __shared__ ushort_t Bsw[2][BN * BK];   // 2 x 8 KB
    __shared__ int segs[BM];

    const int t  = threadIdx.x;
    const int w  = t >> 6;
    const int l  = t & 63;
    const int lm = l & 15;
    const int lq = l >> 4;
    const int r0 = blockIdx.x * BM;
    const size_t kc0 = (size_t)blockIdx.y * KCH;
    const size_t tbase = ((size_t)blockIdx.x * KS + blockIdx.y) * (size_t)(BM * KCH);

    if (t < BM) segs[t] = seg[r0 + t];

    // reg-staged A (f32 -> bf16 -> swizzled ds_write + tiled AbfT store) + gload B
    auto stage = [&](int bi, int ksIdx) {
        const size_t kb = kc0 + (size_t)ksIdx * BK;
#pragma unroll
        for (int q = 0; q < 2; ++q) {
            const int i = q * 256 + t;
            const int r = i >> 3, s = i & 7;
            const float4* g = (const float4*)(A + (size_t)(r0 + r) * N_ATOMS + kb + s * 8);
            float4 a0 = g[0], a1 = g[1];
            short8v vv;
            vv[0] = (short)f2bf(a0.x); vv[1] = (short)f2bf(a0.y);
            vv[2] = (short)f2bf(a0.z); vv[3] = (short)f2bf(a0.w);
            vv[4] = (short)f2bf(a1.x); vv[5] = (short)f2bf(a1.y);
            vv[6] = (short)f2bf(a1.z); vv[7] = (short)f2bf(a1.w);
            const int img = r * BK + ((s ^ (r & 7)) << 3);
            *(short8v*)&Asw[bi][img] = vv;
            *(short8v*)(AbfT + tbase + (size_t)ksIdx * TILE_ELEMS + img) = vv;
        }
#pragma unroll
        for (int q = 0; q < 2; ++q) {
            const int i = q * 256 + t;
            const int r = i >> 3, s = i & 7;
            gload16(hT + (size_t)r * N_ATOMS + kb + ((s ^ (r & 7)) << 3),
                    &Bsw[bi][(q * 256 + w * 64) * 8]);
        }
    };

    f32x4 acc[4];
#pragma unroll
    for (int n = 0; n < 4; ++n) acc[n] = (f32x4){0.f, 0.f, 0.f, 0.f};

    stage(0, 0);   // 2 B-gloads in flight (A reg-loads drained by ds_write dep)

    for (int ks = 0; ks < NSTEP; ++ks) {
        const int bi = ks & 1;
        if (ks + 1 < NSTEP) {
            stage(bi ^ 1, ks + 1);
            asm volatile("s_waitcnt vmcnt(2) lgkmcnt(0)" ::: "memory");
        } else {
            asm volatile("s_waitcnt vmcnt(0) lgkmcnt(0)" ::: "memory");
        }
        __builtin_amdgcn_s_barrier();                         // B1: buf[bi] readable
        asm volatile("" ::: "memory");
        // ---- MFMA phase ----
#pragma unroll
        for (int kki = 0; kki < 2; ++kki) {
            const int sx = ((kki * 4 + lq) ^ (lm & 7)) << 3;
            const int ra = w * 16 + lm;
            short8v a0 = *(const short8v*)&Asw[bi][ra * BK + sx];
            short8v b0 = *(const short8v*)&Bsw[bi][(lm)      * BK + sx];
            short8v b1 = *(const short8v*)&Bsw[bi][(lm + 16) * BK + sx];
            short8v b2 = *(const short8v*)&Bsw[bi][(lm + 32) * BK + sx];
            short8v b3 = *(const short8v*)&Bsw[bi][(lm + 48) * BK + sx];
            acc[0] = __builtin_amdgcn_mfma_f32_16x16x32_bf16(a0, b0, acc[0], 0, 0, 0);
            acc[1] = __builtin_amdgcn_mfma_f32_16x16x32_bf16(a0, b1, acc[1], 0, 0, 0);
            acc[2] = __builtin_amdgcn_mfma_f32_16x16x32_bf16(a0, b2, acc[2], 0, 0, 0);
            acc[3] = __builtin_amdgcn_mfma_f32_16x16x32_bf16(a0, b3, acc[3], 0, 0, 0);
        }
        // ---- SA phase: wave w scans rows w*16..+16 of col c = t&63 ----
        {
            const int c  = t & 63;
            const int cs = c >> 3, cj = c & 7;
            const int kglob = (int)kc0 + ks * BK + c;
            float sacc = 0.f;
            int prev = segs[w * 16];
#pragma unroll
            for (int rr = 0; rr < 16; ++rr) {
                const int row = w * 16 + rr;
                const int m = segs[row];              // uniform within wave
                if (m != prev) {
                    atomicAdd(&SAf32[(size_t)prev * N_ATOMS + kglob], sacc);
                    sacc = 0.f; prev = m;
                }
                sacc += bf2f(Asw[bi][row * BK + ((cs ^ (row & 7)) << 3) + cj]);
            }
            atomicAdd(&SAf32[(size_t)prev * N_ATOMS + kglob], sacc);
        }
        asm volatile("" ::: "memory");
        __builtin_amdgcn_s_barrier();                         // B2: reads of buf[bi] done
        asm volatile("" ::: "memory");
    }

    // C/D layout: col = lane&15, row = (lane>>4)*4 + reg  [m89 verified]
    const int rb = r0 + w * 16 + lq * 4;
#pragma unroll
    for (int j = 0; j < 4; ++j) {
        float* vp = vnext + (size_t)(rb + j) * DIM + lm;
#pragma unroll
        for (int n = 0; n < 4; ++n) atomicAdd(vp + n * 16, acc[n][j]);
    }
}

// ---- tiled-A mm: vnext += A@h, A read as contiguous per-block 64 KB stream ----
__global__ __launch_bounds__(256) void matmul_tiled_kernel(
        const ushort_t* __restrict__ AbfT, const ushort_t* __restrict__ hT,
        float* __restrict__ vnext) {
    __shared__ ushort_t Asw[2][BM * BK];   // 2 x 8 KB
    __shared__ ushort_t Bsw[2][BN * BK];   // 2 x 8 KB

    const int t  = threadIdx.x;
    const int w  = t >> 6;
    const int l  = t & 63;
    const int lm = l & 15;
    const int lq = l >> 4;
    const int r0 = blockIdx.x * BM;
    const size_t kc0 = (size_t)blockIdx.y * KCH;
    const size_t tbase = ((size_t)blockIdx.x * KS + blockIdx.y) * (size_t)(BM * KCH);

    auto stage = [&](int bi, int ksIdx) {
        const size_t kb = kc0 + (size_t)ksIdx * BK;
#pragma unroll
        for (int q = 0; q < 2; ++q) {
            // A: linear 16B/lane from the tile image (swizzle pre-baked)
            gload16(AbfT + tbase + (size_t)ksIdx * TILE_ELEMS + (q * 256 + t) * 8,
                    &Asw[bi][(q * 256 + w * 64) * 8]);
        }
#pragma unroll
        for (int q = 0; q < 2; ++q) {
            const int i = q * 256 + t;
            const int r = i >> 3, s = i & 7;
            gload16(hT + (size_t)r * N_ATOMS + kb + ((s ^ (r & 7)) << 3),
                    &Bsw[bi][(q * 256 + w * 64) * 8]);
        }
    };

    f32x4 acc[4];
#pragma unroll
    for (int n = 0; n < 4; ++n) acc[n] = (f32x4){0.f, 0.f, 0.f, 0.f};

    stage(0, 0);   // 4 loads in flight

    for (int ks = 0; ks < NSTEP; ++ks) {
        const int bi = ks & 1;
        if (ks + 1 < NSTEP) {
            stage(bi ^ 1, ks + 1);                            // +4 newest
            asm volatile("s_waitcnt vmcnt(4)" ::: "memory");  // cur's 4 done
        } else {
            asm volatile("s_waitcnt vmcnt(0)" ::: "memory");
        }
        __builtin_amdgcn_s_barrier();                         // B1: buf[bi] readable
        asm volatile("" ::: "memory");
#pragma unroll
        for (int kki = 0; kki < 2; ++kki) {
            const int sx = ((kki * 4 + lq) ^ (lm & 7)) << 3;
            const int ra = w * 16 + lm;
            short8v a0 = *(const short8v*)&Asw[bi][ra * BK + sx];
            short8v b0 = *(const short8v*)&Bsw[bi][(lm)      * BK + sx];
            short8v b1 = *(const short8v*)&Bsw[bi][(lm + 16) * BK + sx];
            short8v b2 = *(const short8v*)&Bsw[bi][(lm + 32) * BK + sx];
            short8v b3 = *(const short8v*)&Bsw[bi][(lm + 48) * BK + sx];
            acc[0] = __builtin_amdgcn_mfma_f32_16x16x32_bf16(a0, b0, acc[0], 0, 0, 0);
            acc[1] = __builtin_amdgcn_mfma_f32_16x16x32_bf16(a0, b1, acc[1], 0, 0, 0);
            acc[2] = __builtin_amdgcn_mfma_f32_16x16x32_bf16(a0, b2, acc[2], 0, 0, 0);
            acc[3] = __builtin_amdgcn_mfma_f32_16x16x32_bf16(a0, b3, acc[3], 0, 0, 0);
        }
        asm volatile("" ::: "memory");
        __builtin_amdgcn_s_barrier();                         // B2: reads of buf[bi] done
        asm volatile("" ::: "memory");
    }

    // C/D layout: col = lane&15, row = (lane>>4)*4 + reg  [m89 verified]
    const int rb = r0 + w * 16 + lq * 4;
#pragma unroll
    for (int j = 0; j < 4; ++j) {
        float* vp = vnext + (size_t)(rb + j) * DIM + lm;
#pragma unroll
        for (int n = 0; n < 4; ++n) atomicAdd(vp + n * 16, acc[n][j]);
    }
}

// ---- legacy-layout mm (row-major A, stride N_ATOMS) — for the SAbf final ----
__global__ __launch_bounds__(256) void matmul_mfma_kernel(
        const ushort_t* __restrict__ Abf, const ushort_t* __restrict__ hT,
        float* __restrict__ vnext) {
    __shared__ ushort_t Asw[2][BM * BK];
    __shared__ ushort_t Bsw[2][BN * BK];

    const int t  = threadIdx.x;
    const int w  = t >> 6;
    const int l  = t & 63;
    const int lm = l & 15;
    const int lq = l >> 4;
    const int r0 = blockIdx.x * BM;
    const size_t kc0 = (size_t)blockIdx.y * KCH;

    auto stage = [&](int bi, size_t kb) {
#pragma unroll
        for (int q = 0; q < 2; ++q) {
            const int i = q * 256 + t;
            const int r = i >> 3, s = i & 7;
            gload16(Abf + (size_t)(r0 + r) * N_ATOMS + kb + ((s ^ (r & 7)) << 3),
                    &Asw[bi][(q * 256 + w * 64) * 8]);
        }
#pragma unroll
        for (int q = 0; q < 2; ++q) {
            const int i = q * 256 + t;
            const int r = i >> 3, s = i & 7;
            gload16(hT + (size_t)r * N_ATOMS + kb + ((s ^ (r & 7)) << 3),
                    &Bsw[bi][(q * 256 + w * 64) * 8]);
        }
    };

    f32x4 acc[4];
#pragma unroll
    for (int n = 0; n < 4; ++n) acc[n] = (f32x4){0.f, 0.f, 0.f, 0.f};

    stage(0, kc0);

    for (int ks = 0; ks < NSTEP; ++ks) {
        const int bi = ks & 1;
        if (ks + 1 < NSTEP) {
            stage(bi ^ 1, kc0 + (size_t)(ks + 1) * BK);
            asm volatile("s_waitcnt vmcnt(4)" ::: "memory");
        } else {
            asm volatile("s_waitcnt vmcnt(0)" ::: "memory");
        }
        __builtin_amdgcn_s_barrier();
        asm volatile("" ::: "memory");
#pragma unroll
        for (int kki = 0; kki < 2; ++kki) {
            const int sx = ((kki * 4 + lq) ^ (lm & 7)) << 3;
            const int ra = w * 16 + lm;
            short8v a0 = *(const short8v*)&Asw[bi][ra * BK + sx];
            short8v b0 = *(const short8v*)&Bsw[bi][(lm)      * BK + sx];
            short8v b1 = *(const short8v*)&Bsw[bi][(lm + 16) * BK + sx];
            short8v b2 = *(const short8v*)&Bsw[bi][(lm + 32) * BK + sx];
            short8v b3 = *(const short8v*)&Bsw[bi][(lm + 48) * BK + sx];
            acc[0] = __builtin_amdgcn_mfma_f32_16x16x32_bf16(a0, b0, acc[0], 0, 0, 0);
            acc[1] = __builtin_amdgcn_mfma_f32_16x16x32_bf16(a0, b1, acc[1], 0, 0, 0);
            acc[2] = __builtin_amdgcn_mfma_f32_16x16x32_bf16(a0, b2, acc[2], 0, 0, 0);
            acc[3] = __builtin_amdgcn_mfma_f32_16x16x32_bf16(a0, b3, acc[3], 0, 0, 0);
        }
        asm volatile("" ::: "memory");
        __builtin_amdgcn_s_barrier();
        asm volatile("" ::: "memory");
    }

    const int rb = r0 + w * 16 + lq * 4;
#pragma unroll
    for (int j = 0; j < 4; ++j) {
        float* vp = vnext + (size_t)(rb + j) * DIM + lm;
#pragma unroll
        for (int n = 0; n < 4; ++n) atomicAdd(vp + n * 16, acc[n][j]);
    }
}

extern "C" void kernel_launch(void* const* d_in, const int* in_sizes, int n_in,
                              void* d_out, int out_size, void* d_ws, size_t ws_size,
                              hipStream_t stream) {
    const int*   fp    = (const int*)d_in[0];
    const float* A     = (const float*)d_in[1];
    const int*   seg   = (const int*)d_in[2];
    const float* table = (const float*)d_in[3];
    const float* W     = (const float*)d_in[4];
    const float* b     = (const float*)d_in[5];
    float* out = (float*)d_out;

    char* ws = (char*)d_ws;
    float*    vA    = (float*)    ws;                         // 2 MB
    float*    vB    = (float*)   (ws + 2097152);              // 2 MB
    ushort_t* hT    = (ushort_t*)(ws + 4194304);              // 1 MB
    float*    SAf32 = (float*)   (ws + 5242880);              // 8 MB
    ushort_t* SAbf  = (ushort_t*)(ws + 13631488);             // 4 MB
    ushort_t* AbfT  = (ushort_t*)(ws + 17825792);             // 134 MB (tiled)

    (void)hipMemsetAsync(SAf32, 0, (size_t)N_MOL * N_ATOMS * 4, stream);
    (void)hipMemsetAsync(out, 0, (size_t)out_size * 4, stream);

    dim3 mmgrid(N_ATOMS / BM, KS);

    // layer 0: vA = h0; one pass over f32 A: vA += A@h0, AbfT (tiled), SAf32
    fused_linear_kernel<1, 0><<<N_ATOMS / 32, 256, 0, stream>>>(
        fp, table, nullptr, seg, W, b, vA, hT, nullptr);
    matmul_cvtsa_kernel<<<mmgrid, 256, 0, stream>>>(A, seg, AbfT, SAf32, hT, vA);
    packsa_kernel<<<(N_MOL * N_ATOMS) / (256 * 8), 256, 0, stream>>>(SAf32, SAbf);
    // layer 1: vB = h1, vB += A@h1 (tiled contiguous A stream)
    fused_linear_kernel<0, 0><<<N_ATOMS / 32, 256, 0, stream>>>(
        fp, table, vA, seg, W + DIM * DIM, b + DIM, vB, hT, nullptr);
    matmul_tiled_kernel<<<mmgrid, 256, 0, stream>>>(AbfT, hT, vB);
    // layer 2: h2 -> hT + segsum(h2) atomically into out
    fused_linear_kernel<0, 1><<<N_ATOMS / 32, 256, 0, stream>>>(
        fp, table, vB, seg, W + 2 * DIM * DIM, b + 2 * DIM, nullptr, hT, out);
    // telescoped final matmul: out += (S*A) @ h2
    matmul_mfma_kernel<<<dim3(N_MOL / BM, KS), 256, 0, stream>>>(SAbf, hT, out);
}

// Round 16
// 183.335 us; speedup vs baseline: 1.0481x; 1.0481x over previous
//
#include <hip/hip_runtime.h>

#define N_ATOMS 8192
#define DIM 64
#define N_MOL 256
#define KS 16                 // cvtsa k-splits (defines AbfT tile layout)
#define KCH (N_ATOMS / KS)    // 512
#define MM_KS 8               // mm1 k-splits (deep pipeline)
#define MM_KCH (N_ATOMS / MM_KS)  // 1024
#define MM_NSTEP (MM_KCH / 64)    // 16
#define BM 64
#define BN 64
#define BK 64
#define NSTEP (KCH / BK)      // 8
#define TILE_ELEMS (BM * BK)  // 4096 ushorts = 8 KB per k-step image

typedef __attribute__((ext_vector_type(8))) short short8v;
typedef __attribute__((ext_vector_type(4))) float f32x4;
typedef unsigned short ushort_t;

// f32 -> bf16 RTNE (inputs finite)
__device__ __forceinline__ ushort_t f2bf(float x) {
    unsigned u = __float_as_uint(x);
    u += 0x7fffu + ((u >> 16) & 1u);
    return (ushort_t)(u >> 16);
}
__device__ __forceinline__ float bf2f(ushort_t u) {
    return __uint_as_float(((unsigned)u) << 16);
}

// async global->LDS, 16B per lane, LDS dest = wave-uniform base + lane*16
__device__ __forceinline__ void gload16(const void* gsrc, void* ldst) {
    __builtin_amdgcn_global_load_lds(
        (const __attribute__((address_space(1))) void*)gsrc,
        (__attribute__((address_space(3))) void*)ldst, 16, 0, 0);
}

// ---- pack SAf32 -> SAbf (bf16, dense 256 x 8192, row stride N_ATOMS) ----
__global__ __launch_bounds__(256) void packsa_kernel(
        const float* __restrict__ SAf32, ushort_t* __restrict__ SAbf) {
    const size_t i = ((size_t)blockIdx.x * 256 + threadIdx.x) * 8;
    float4 x0 = *(const float4*)(SAf32 + i);
    float4 x1 = *(const float4*)(SAf32 + i + 4);
    short8v v;
    v[0] = (short)f2bf(x0.x); v[1] = (short)f2bf(x0.y);
    v[2] = (short)f2bf(x0.z); v[3] = (short)f2bf(x0.w);
    v[4] = (short)f2bf(x1.x); v[5] = (short)f2bf(x1.y);
    v[6] = (short)f2bf(x1.z); v[7] = (short)f2bf(x1.w);
    *(short8v*)(SAbf + i) = v;
}

// ---- fused linear: v = (FIRST ? embed : vprev); h = relu(W v + b)
// writes hT (bf16 [DIM][N_ATOMS]); if !LAST writes vnext = h (f32);
// if LAST instead accumulates segsum(h) into out via scan+atomicAdd.
template <int FIRST, int LAST>
__global__ __launch_bounds__(256) void fused_linear_kernel(
        const int* __restrict__ fp, const float* __restrict__ table,
        const float* __restrict__ vprev, const int* __restrict__ seg,
        const float* __restrict__ W, const float* __restrict__ b,
        float* __restrict__ vnext, ushort_t* __restrict__ hT,
        float* __restrict__ out) {
    __shared__ float Ws[DIM][DIM + 1];
    __shared__ float vsT[DIM][36];
    __shared__ int segs[32];

    const int t = threadIdx.x;
    const int n0 = blockIdx.x * 32;
    if (LAST && t < 32) segs[t] = seg[n0 + t];
    for (int i = t; i < DIM * DIM; i += 256) Ws[i >> 6][i & 63] = W[i];
    for (int i = t; i < 32 * DIM; i += 256) {
        const int nl = i >> 6, d = i & 63;
        const size_t n = n0 + nl;
        float val;
        if (FIRST) val = table[(size_t)fp[n] * DIM + d];
        else       val = vprev[n * DIM + d];
        vsT[d][nl] = val;
    }
    __syncthreads();

    const int e = t & 63;
    const int g = t >> 6;
    float acc[8];
    const float be = b[e];
#pragma unroll
    for (int i = 0; i < 8; ++i) acc[i] = be;

    for (int d = 0; d < DIM; ++d) {
        const float w = Ws[e][d];
        const float4* vp = (const float4*)&vsT[d][g * 8];
        float4 x0 = vp[0], x1 = vp[1];
        acc[0] += w * x0.x; acc[1] += w * x0.y; acc[2] += w * x0.z; acc[3] += w * x0.w;
        acc[4] += w * x1.x; acc[5] += w * x1.y; acc[6] += w * x1.z; acc[7] += w * x1.w;
    }

    ushort_t hb[8];
    float seg_acc = 0.f;
    int prev = LAST ? segs[g * 8] : 0;
#pragma unroll
    for (int i = 0; i < 8; ++i) {
        float hv = acc[i] > 0.f ? acc[i] : 0.f;
        if (LAST) {
            const int m = segs[g * 8 + i];
            if (m != prev) {
                atomicAdd(&out[(size_t)prev * DIM + e], seg_acc);
                seg_acc = 0.f; prev = m;
            }
            seg_acc += hv;
        } else {
            vnext[(size_t)(n0 + g * 8 + i) * DIM + e] = hv;
        }
        hb[i] = f2bf(hv);
    }
    if (LAST) atomicAdd(&out[(size_t)prev * DIM + e], seg_acc);
    *(short8v*)(hT + (size_t)e * N_ATOMS + n0 + g * 8) = *(short8v*)&hb[0];
}

// ---- layer-0 mega kernel (r14-validated): one pass over f32 A:
//   vnext += A@h0 (MFMA), AbfT = tiled bf16(A), SAf32 += segment col-sums.
__global__ __launch_bounds__(256) void matmul_cvtsa_kernel(
        const float* __restrict__ A, const int* __restrict__ seg,
        ushort_t* __restrict__ AbfT, float* __restrict__ SAf32,
        const ushort_t* __restrict__ hT, float* __restrict__ vnext) {
    __shared__ ushort_t Asw[2][BM * BK];   // 2 x 8 KB
    __shared__ ushort_t Bsw[2][BN * BK];   // 2 x 8 KB
    __shared__ int segs[BM];

    const int t  = threadIdx.x;
    const int w  = t >> 6;
    const int l  = t & 63;
    const int lm = l & 15;
    const int lq = l >> 4;
    const int r0 = blockIdx.x * BM;
    const size_t kc0 = (size_t)blockIdx.y * KCH;
    const size_t tbase = ((size_t)blockIdx.x * KS + blockIdx.y) * (size_t)(BM * KCH);

    if (t < BM) segs[t] = seg[r0 + t];

    auto stage = [&](int bi, int ksIdx) {
        const size_t kb = kc0 + (size_t)ksIdx * BK;
#pragma unroll
        for (int q = 0; q < 2; ++q) {
            const int i = q * 256 + t;
            const int r = i >> 3, s = i & 7;
            const float4* g = (const float4*)(A + (size_t)(r0 + r) * N_ATOMS + kb + s * 8);
            float4 a0 = g[0], a1 = g[1];
            short8v vv;
            vv[0] = (short)f2bf(a0.x); vv[1] = (short)f2bf(a0.y);
            vv[2] = (short)f2bf(a0.z); vv[3] = (short)f2bf(a0.w);
            vv[4] = (short)f2bf(a1.x); vv[5] = (short)f2bf(a1.y);
            vv[6] = (short)f2bf(a1.z); vv[7] = (short)f2bf(a1.w);
            const int img = r * BK + ((s ^ (r & 7)) << 3);
            *(short8v*)&Asw[bi][img] = vv;
            *(short8v*)(AbfT + tbase + (size_t)ksIdx * TILE_ELEMS + img) = vv;
        }
#pragma unroll
        for (int q = 0; q < 2; ++q) {
            const int i = q * 256 + t;
            const int r = i >> 3, s = i & 7;
            gload16(hT + (size_t)r * N_ATOMS + kb + ((s ^ (r & 7)) << 3),
                    &Bsw[bi][(q * 256 + w * 64) * 8]);
        }
    };

    f32x4 acc[4];
#pragma unroll
    for (int n = 0; n < 4; ++n) acc[n] = (f32x4){0.f, 0.f, 0.f, 0.f};

    stage(0, 0);

    for (int ks = 0; ks < NSTEP; ++ks) {
        const int bi = ks & 1;
        if (ks + 1 < NSTEP) {
            stage(bi ^ 1, ks + 1);
            asm volatile("s_waitcnt vmcnt(2) lgkmcnt(0)" ::: "memory");
        } else {
            asm volatile("s_waitcnt vmcnt(0) lgkmcnt(0)" ::: "memory");
        }
        __builtin_amdgcn_s_barrier();
        asm volatile("" ::: "memory");
#pragma unroll
        for (int kki = 0; kki < 2; ++kki) {
            const int sx = ((kki * 4 + lq) ^ (lm & 7)) << 3;
            const int ra = w * 16 + lm;
            short8v a0 = *(const short8v*)&Asw[bi][ra * BK + sx];
            short8v b0 = *(const short8v*)&Bsw[bi][(lm)      * BK + sx];
            short8v b1 = *(const short8v*)&Bsw[bi][(lm + 16) * BK + sx];
            short8v b2 = *(const short8v*)&Bsw[bi][(lm + 32) * BK + sx];
            short8v b3 = *(const short8v*)&Bsw[bi][(lm + 48) * BK + sx];
            acc[0] = __builtin_amdgcn_mfma_f32_16x16x32_bf16(a0, b0, acc[0], 0, 0, 0);
            acc[1] = __builtin_amdgcn_mfma_f32_16x16x32_bf16(a0, b1, acc[1], 0, 0, 0);
            acc[2] = __builtin_amdgcn_mfma_f32_16x16x32_bf16(a0, b2, acc[2], 0, 0, 0);
            acc[3] = __builtin_amdgcn_mfma_f32_16x16x32_bf16(a0, b3, acc[3], 0, 0, 0);
        }
        // ---- SA phase ----
        {
            const int c  = t & 63;
            const int cs = c >> 3, cj = c & 7;
            const int kglob = (int)kc0 + ks * BK + c;
            float sacc = 0.f;
            int prev = segs[w * 16];
#pragma unroll
            for (int rr = 0; rr < 16; ++rr) {
                const int row = w * 16 + rr;
                const int m = segs[row];
                if (m != prev) {
                    atomicAdd(&SAf32[(size_t)prev * N_ATOMS + kglob], sacc);
                    sacc = 0.f; prev = m;
                }
                sacc += bf2f(Asw[bi][row * BK + ((cs ^ (row & 7)) << 3) + cj]);
            }
            atomicAdd(&SAf32[(size_t)prev * N_ATOMS + kglob], sacc);
        }
        asm volatile("" ::: "memory");
        __builtin_amdgcn_s_barrier();
        asm volatile("" ::: "memory");
    }

    const int rb = r0 + w * 16 + lq * 4;
#pragma unroll
    for (int j = 0; j < 4; ++j) {
        float* vp = vnext + (size_t)(rb + j) * DIM + lm;
#pragma unroll
        for (int n = 0; n < 4; ++n) atomicAdd(vp + n * 16, acc[n][j]);
    }
}

// ---- mm1: 3-buffer, 2-ahead counted-vmcnt pipeline (T3/T4 depth).
// grid (N_ATOMS/BM, MM_KS); block covers 2 consecutive cvtsa tiles (KS layout).
// vmcnt(8) = 2 newest stages (4 loads each) may remain outstanding.
__global__ __launch_bounds__(256) void matmul_deep_kernel(
        const ushort_t* __restrict__ AbfT, const ushort_t* __restrict__ hT,
        float* __restrict__ vnext) {
    __shared__ ushort_t Asw[3][BM * BK];   // 3 x 8 KB
    __shared__ ushort_t Bsw[3][BN * BK];   // 3 x 8 KB

    const int t  = threadIdx.x;
    const int w  = t >> 6;
    const int l  = t & 63;
    const int lm = l & 15;
    const int lq = l >> 4;
    const int r0 = blockIdx.x * BM;
    const int by0 = blockIdx.y * 2;                 // first cvtsa tile index
    const size_t kc0 = (size_t)blockIdx.y * MM_KCH;

    auto stage = [&](int bi, int ksIdx) {
        const size_t kb = kc0 + (size_t)ksIdx * BK;
        const size_t tb = ((size_t)blockIdx.x * KS + by0 + (ksIdx >> 3)) * (size_t)(BM * KCH)
                        + (size_t)(ksIdx & 7) * TILE_ELEMS;
#pragma unroll
        for (int q = 0; q < 2; ++q) {
            gload16(AbfT + tb + (size_t)(q * 256 + t) * 8,
                    &Asw[bi][(q * 256 + w * 64) * 8]);
        }
#pragma unroll
        for (int q = 0; q < 2; ++q) {
            const int i = q * 256 + t;
            const int r = i >> 3, s = i & 7;
            gload16(hT + (size_t)r * N_ATOMS + kb + ((s ^ (r & 7)) << 3),
                    &Bsw[bi][(q * 256 + w * 64) * 8]);
        }
    };

    f32x4 acc[4];
#pragma unroll
    for (int n = 0; n < 4; ++n) acc[n] = (f32x4){0.f, 0.f, 0.f, 0.f};

    stage(0, 0);
    stage(1, 1);   // 8 loads in flight (2 stages deep)

    for (int ks = 0; ks < MM_NSTEP; ++ks) {
        const int bi = ks % 3;
        if (ks + 2 < MM_NSTEP) {
            // overwrites buf[(ks-1)%3]: all waves' reads of it completed at B2(ks-1)
            stage((ks + 2) % 3, ks + 2);
            asm volatile("s_waitcnt vmcnt(8)" ::: "memory");   // stage(ks) done
        } else if (ks + 1 < MM_NSTEP) {
            asm volatile("s_waitcnt vmcnt(4)" ::: "memory");   // stage(ks) done
        } else {
            asm volatile("s_waitcnt vmcnt(0)" ::: "memory");
        }
        __builtin_amdgcn_s_barrier();                          // B1: buf[bi] readable
        asm volatile("" ::: "memory");
#pragma unroll
        for (int kki = 0; kki < 2; ++kki) {
            const int sx = ((kki * 4 + lq) ^ (lm & 7)) << 3;
            const int ra = w * 16 + lm;
            short8v a0 = *(const short8v*)&Asw[bi][ra * BK + sx];
            short8v b0 = *(const short8v*)&Bsw[bi][(lm)      * BK + sx];
            short8v b1 = *(const short8v*)&Bsw[bi][(lm + 16) * BK + sx];
            short8v b2 = *(const short8v*)&Bsw[bi][(lm + 32) * BK + sx];
            short8v b3 = *(const short8v*)&Bsw[bi][(lm + 48) * BK + sx];
            acc[0] = __builtin_amdgcn_mfma_f32_16x16x32_bf16(a0, b0, acc[0], 0, 0, 0);
            acc[1] = __builtin_amdgcn_mfma_f32_16x16x32_bf16(a0, b1, acc[1], 0, 0, 0);
            acc[2] = __builtin_amdgcn_mfma_f32_16x16x32_bf16(a0, b2, acc[2], 0, 0, 0);
            acc[3] = __builtin_amdgcn_mfma_f32_16x16x32_bf16(a0, b3, acc[3], 0, 0, 0);
        }
        asm volatile("" ::: "memory");
        __builtin_amdgcn_s_barrier();                          // B2: reads of buf[bi] done
        asm volatile("" ::: "memory");
    }

    // C/D layout: col = lane&15, row = (lane>>4)*4 + reg  [m89 verified]
    const int rb = r0 + w * 16 + lq * 4;
#pragma unroll
    for (int j = 0; j < 4; ++j) {
        float* vp = vnext + (size_t)(rb + j) * DIM + lm;
#pragma unroll
        for (int n = 0; n < 4; ++n) atomicAdd(vp + n * 16, acc[n][j]);
    }
}

// ---- legacy-layout mm (row-major A, stride N_ATOMS) — for the SAbf final ----
__global__ __launch_bounds__(256) void matmul_mfma_kernel(
        const ushort_t* __restrict__ Abf, const ushort_t* __restrict__ hT,
        float* __restrict__ vnext) {
    __shared__ ushort_t Asw[2][BM * BK];
    __shared__ ushort_t Bsw[2][BN * BK];

    const int t  = threadIdx.x;
    const int w  = t >> 6;
    const int l  = t & 63;
    const int lm = l & 15;
    const int lq = l >> 4;
    const int r0 = blockIdx.x * BM;
    const size_t kc0 = (size_t)blockIdx.y * KCH;

    auto stage = [&](int bi, size_t kb) {
#pragma unroll
        for (int q = 0; q < 2; ++q) {
            const int i = q * 256 + t;
            const int r = i >> 3, s = i & 7;
            gload16(Abf + (size_t)(r0 + r) * N_ATOMS + kb + ((s ^ (r & 7)) << 3),
                    &Asw[bi][(q * 256 + w * 64) * 8]);
        }
#pragma unroll
        for (int q = 0; q < 2; ++q) {
            const int i = q * 256 + t;
            const int r = i >> 3, s = i & 7;
            gload16(hT + (size_t)r * N_ATOMS + kb + ((s ^ (r & 7)) << 3),
                    &Bsw[bi][(q * 256 + w * 64) * 8]);
        }
    };

    f32x4 acc[4];
#pragma unroll
    for (int n = 0; n < 4; ++n) acc[n] = (f32x4){0.f, 0.f, 0.f, 0.f};

    stage(0, kc0);

    for (int ks = 0; ks < NSTEP; ++ks) {
        const int bi = ks & 1;
        if (ks + 1 < NSTEP) {
            stage(bi ^ 1, kc0 + (size_t)(ks + 1) * BK);
            asm volatile("s_waitcnt vmcnt(4)" ::: "memory");
        } else {
            asm volatile("s_waitcnt vmcnt(0)" ::: "memory");
        }
        __builtin_amdgcn_s_barrier();
        asm volatile("" ::: "memory");
#pragma unroll
        for (int kki = 0; kki < 2; ++kki) {
            const int sx = ((kki * 4 + lq) ^ (lm & 7)) << 3;
            const int ra = w * 16 + lm;
            short8v a0 = *(const short8v*)&Asw[bi][ra * BK + sx];
            short8v b0 = *(const short8v*)&Bsw[bi][(lm)      * BK + sx];
            short8v b1 = *(const short8v*)&Bsw[bi][(lm + 16) * BK + sx];
            short8v b2 = *(const short8v*)&Bsw[bi][(lm + 32) * BK + sx];
            short8v b3 = *(const short8v*)&Bsw[bi][(lm + 48) * BK + sx];
            acc[0] = __builtin_amdgcn_mfma_f32_16x16x32_bf16(a0, b0, acc[0], 0, 0, 0);
            acc[1] = __builtin_amdgcn_mfma_f32_16x16x32_bf16(a0, b1, acc[1], 0, 0, 0);
            acc[2] = __builtin_amdgcn_mfma_f32_16x16x32_bf16(a0, b2, acc[2], 0, 0, 0);
            acc[3] = __builtin_amdgcn_mfma_f32_16x16x32_bf16(a0, b3, acc[3], 0, 0, 0);
        }
        asm volatile("" ::: "memory");
        __builtin_amdgcn_s_barrier();
        asm volatile("" ::: "memory");
    }

    const int rb = r0 + w * 16 + lq * 4;
#pragma unroll
    for (int j = 0; j < 4; ++j) {
        float* vp = vnext + (size_t)(rb + j) * DIM + lm;
#pragma unroll
        for (int n = 0; n < 4; ++n) atomicAdd(vp + n * 16, acc[n][j]);
    }
}

extern "C" void kernel_launch(void* const* d_in, const int* in_sizes, int n_in,
                              void* d_out, int out_size, void* d_ws, size_t ws_size,
                              hipStream_t stream) {
    const int*   fp    = (const int*)d_in[0];
    const float* A     = (const float*)d_in[1];
    const int*   seg   = (const int*)d_in[2];
    const float* table = (const float*)d_in[3];
    const float* W     = (const float*)d_in[4];
    const float* b     = (const float*)d_in[5];
    float* out = (float*)d_out;

    char* ws = (char*)d_ws;
    float*    vA    = (float*)    ws;                         // 2 MB
    float*    vB    = (float*)   (ws + 2097152);              // 2 MB
    ushort_t* hT    = (ushort_t*)(ws + 4194304);              // 1 MB
    float*    SAf32 = (float*)   (ws + 5242880);              // 8 MB
    ushort_t* SAbf  = (ushort_t*)(ws + 13631488);             // 4 MB
    ushort_t* AbfT  = (ushort_t*)(ws + 17825792);             // 134 MB (tiled)

    (void)hipMemsetAsync(SAf32, 0, (size_t)N_MOL * N_ATOMS * 4, stream);
    (void)hipMemsetAsync(out, 0, (size_t)out_size * 4, stream);

    // layer 0: vA = h0; one pass over f32 A: vA += A@h0, AbfT (tiled), SAf32
    fused_linear_kernel<1, 0><<<N_ATOMS / 32, 256, 0, stream>>>(
        fp, table, nullptr, seg, W, b, vA, hT, nullptr);
    matmul_cvtsa_kernel<<<dim3(N_ATOMS / BM, KS), 256, 0, stream>>>(
        A, seg, AbfT, SAf32, hT, vA);
    packsa_kernel<<<(N_MOL * N_ATOMS) / (256 * 8), 256, 0, stream>>>(SAf32, SAbf);
    // layer 1: vB = h1, vB += A@h1 (deep 3-buffer pipeline)
    fused_linear_kernel<0, 0><<<N_ATOMS / 32, 256, 0, stream>>>(
        fp, table, vA, seg, W + DIM * DIM, b + DIM, vB, hT, nullptr);
    matmul_deep_kernel<<<dim3(N_ATOMS / BM, MM_KS), 256, 0, stream>>>(AbfT, hT, vB);
    // layer 2: h2 -> hT + segsum(h2) atomically into out
    fused_linear_kernel<0, 1><<<N_ATOMS / 32, 256, 0, stream>>>(
        fp, table, vB, seg, W + 2 * DIM * DIM, b + 2 * DIM, nullptr, hT, out);
    // telescoped final matmul: out += (S*A) @ h2
    matmul_mfma_kernel<<<dim3(N_MOL / BM, KS), 256, 0, stream>>>(SAbf, hT, out);
}